// Round 6
// baseline (454.820 us; speedup 1.0000x reference)
//
#include <hip/hip_runtime.h>

// M=512, N=2048, B=4, L=20, H density 0.02 (row weight ~41, col weight ~10).
// COLUMN-partitioned: block (b,r) owns columns [r*256,(r+1)*256) and ALL edges
// in them. colsum/beliefs/loss are block-local; only per-row partial products
// (512 floats) cross blocks per layer (vs 2*2048 write + 18K read when
// row-partitioned). Exchange volume is the measured bottleneck (R5: 11.4us/layer).
#define MM 512
#define NN 2048
#define BB 4
#define LL 20
#define MAXDEG 128      // per-row cap (~13 sigma)
#define NT    1024
#define RR    8         // blocks per batch (column-partitioned)
#define COLSB 256       // NN / RR columns per block
#define SLOTS 4096      // padded edge slots per block (~2621 expected, +29 sigma)
#define EPSV  1e-6f

// ---------------- workspace layout (bytes) ----------------
#define WS_ROW_DEG   0          // int[512]
#define WS_ROW_PAD   2048       // int[512*128]
#define WS_ROW_OFFF  264192     // float[512]
#define WS_DEG_RB    266240     // int[RR*512]   per-slice row degrees
#define WS_RPTR_RB   282624     // int[RR*513]   per-slice row prefix (block-local)
#define WS_EDGE_CS   299040     // uint[RR*SLOTS] (row<<16|col), slice-major, row-sorted
#define WS_WDE_P     430112     // float[L*RR*SLOTS]  per-block padded, 16B-aligned segs
#define WS_MWDE_P    3051552    // float[L*RR*SLOTS]
#define WS_PP        5672992    // float[2*B*RR*512] row-product partials (parity dbuf)
#define WS_BAR       5804064    // int[B*64] barrier counters (memset 0 each launch)
// total ~5.81 MB

// ---- k1: one wave per row, ballot-compact H row into padded list ----
__global__ __launch_bounds__(64)
void build_rows(const float* __restrict__ H, int* __restrict__ row_deg,
                int* __restrict__ row_pad, float* __restrict__ row_offf) {
    int i = blockIdx.x, lane = threadIdx.x;
    const float* hrow = H + (size_t)i * NN;
    float v[32];
    #pragma unroll
    for (int c = 0; c < 32; ++c) v[c] = hrow[c * 64 + lane];
    int base = 0;
    #pragma unroll
    for (int c = 0; c < 32; ++c) {
        bool pred = v[c] != 0.0f;
        unsigned long long mask = __ballot(pred);
        int before = __popcll(mask & ((1ull << lane) - 1ull));
        if (pred) {
            int k = base + before;
            if (k < MAXDEG) row_pad[i * MAXDEG + k] = c * 64 + lane;
        }
        base += __popcll(mask);
    }
    if (lane == 0) {
        row_deg[i] = base < MAXDEG ? base : MAXDEG;
        // off-support entries contribute clip(1.0)=1-eps each to the row product
        row_offf[i] = powf(1.0f - EPSV, (float)(NN - base));
    }
}

// ---- k2: per (slice, row) degree counts ----
__global__ __launch_bounds__(512)
void count_slices(const int* __restrict__ row_deg, const int* __restrict__ row_pad,
                  int* __restrict__ deg_rb) {
    int i = threadIdx.x;
    int deg = row_deg[i];
    int cnt[RR];
    #pragma unroll
    for (int r = 0; r < RR; ++r) cnt[r] = 0;
    for (int k = 0; k < deg; ++k) {
        int c = row_pad[i * MAXDEG + k];
        cnt[c >> 8]++;                       // slice = col/256
    }
    #pragma unroll
    for (int r = 0; r < RR; ++r) deg_rb[r * MM + i] = cnt[r];
}

// ---- k2b: per-slice exclusive prefix over rows -> block-local edge offsets ----
__global__ __launch_bounds__(512)
void scan_slices(const int* __restrict__ deg_rb, int* __restrict__ rptr_rb) {
    __shared__ int tmp[512];
    int r = blockIdx.x, t = threadIdx.x;
    tmp[t] = deg_rb[r * MM + t];
    __syncthreads();
    for (int off = 1; off < 512; off <<= 1) {
        int v = (t >= off) ? tmp[t - off] : 0;
        __syncthreads();
        tmp[t] += v;
        __syncthreads();
    }
    if (t == 0) rptr_rb[r * 513] = 0;
    rptr_rb[r * 513 + t + 1] = tmp[t];
}

// ---- k3: fill slice-major, row-sorted edge lists ----
__global__ __launch_bounds__(512)
void fill_cs(const int* __restrict__ row_deg, const int* __restrict__ row_pad,
             const int* __restrict__ rptr_rb, unsigned* __restrict__ edge_cs) {
    int i = threadIdx.x;
    int deg = row_deg[i];
    int cnt[RR];
    #pragma unroll
    for (int r = 0; r < RR; ++r) cnt[r] = 0;
    for (int k = 0; k < deg; ++k) {
        int c = row_pad[i * MAXDEG + k];
        int r = c >> 8;
        int pos = rptr_rb[r * 513 + i] + cnt[r]++;
        if (pos < SLOTS)
            edge_cs[r * SLOTS + pos] = ((unsigned)i << 16) | (unsigned)c;
    }
}

// ---- k4: gather dense weights into per-block padded segments [l][r][s] ----
__global__ __launch_bounds__(256)
void gather_weights(const float* __restrict__ w_de, const float* __restrict__ mw_de,
                    const unsigned* __restrict__ edge_cs, const int* __restrict__ rptr_rb,
                    float* __restrict__ wde_p, float* __restrict__ mwde_p) {
    int idx = blockIdx.x * 256 + threadIdx.x;       // 0 .. L*RR*SLOTS-1
    int l = idx / (RR * SLOTS);
    int rem = idx - l * (RR * SLOTS);
    int r = rem / SLOTS, s = rem - r * SLOTS;
    int tot = rptr_rb[r * 513 + MM];
    if (tot > SLOTS) tot = SLOTS;
    if (s < tot) {
        unsigned pk = edge_cs[r * SLOTS + s];
        size_t src = (size_t)l * MM * NN + (size_t)(pk >> 16) * NN + (pk & 0xffffu);
        wde_p[idx]  = w_de[src];
        mwde_p[idx] = mw_de[src];
    } else {
        wde_p[idx]  = 0.0f;    // padded slots: defined zeros
        mwde_p[idx] = 0.0f;
    }
}

// ---- device-scope barrier across the RR blocks of one batch ----
// No __threadfence (agent fence = full L2 writeback+invalidate per layer, R5
// confirmed removing it helps). Exchanged data uses agent-scope RELAXED atomic
// load/store (coherent at the MALL, cross-XCD valid). Release: __syncthreads
// drains vmcnt(0) per wave before s_barrier; tid0 waitcnt covers its own ops.
// Acquire: control dependency + trailing __syncthreads. Fresh counter per layer.
// FAILSAFE: bounded spin (~100ms) -> wrong answer instead of container kill.
__device__ __forceinline__ void grid_barrier(int* ctr) {
    __syncthreads();
    if (threadIdx.x == 0) {
        asm volatile("s_waitcnt vmcnt(0)" ::: "memory");
        __hip_atomic_fetch_add(ctr, 1, __ATOMIC_RELAXED, __HIP_MEMORY_SCOPE_AGENT);
        int it = 0;
        while (__hip_atomic_load(ctr, __ATOMIC_RELAXED, __HIP_MEMORY_SCOPE_AGENT) < RR) {
            __builtin_amdgcn_s_sleep(1);
            if (++it > (1 << 22)) break;     // bounded failsafe
        }
        asm volatile("" ::: "memory");
    }
    __syncthreads();
}

// ---- main BP kernel: 32 blocks = 4 batches x 8 COLUMN-partitions ----
__global__ __launch_bounds__(NT, 4)
void nbp_main(const int* __restrict__ synd, const int* __restrict__ errs,
              const float* __restrict__ llrs,
              const float* __restrict__ w_llr, const float* __restrict__ mw_llr,
              const float* __restrict__ rhos, const float* __restrict__ resw,
              const int* __restrict__ rptr_rb, const float* __restrict__ row_offf,
              const unsigned* __restrict__ edge_cs,
              const float* __restrict__ wde_p, const float* __restrict__ mwde_p,
              float* __restrict__ pp, int* __restrict__ bar,
              float* __restrict__ out) {
    __shared__ float d_sb[SLOTS];          // 16 KB block-local d
    __shared__ float colsum_s[COLSB];      // owned columns: full colsum (local!)
    __shared__ float bel_s[COLSB];         // belief accum (local!)
    __shared__ float ncs_s[COLSB];         // next-layer colsum accum (local!)
    __shared__ float llrs_s[COLSB];
    __shared__ float ef_s[COLSB];          // 1 - error
    __shared__ float rowprod_s[MM];        // full row products after combine
    __shared__ float rp_coef[MM];          // row_offf * (-1)^syndrome
    __shared__ int   rowptr_s[MM + 1];     // block-local row segment offsets
    __shared__ float rho_n[LL];
    __shared__ float red[16];
    // ~28 KB total

    const int blk = blockIdx.x;
    const int b = blk & 3, r = blk >> 2;
    const int tid = threadIdx.x;
    const int lane = tid & 63, wave = tid >> 6;

    int* bar_b = bar + b * 64;

    // ---- prologue ----
    if (tid == 0) {
        float mx = -1e30f;
        for (int l = 0; l < LL; ++l) mx = fmaxf(mx, rhos[l]);
        float s = 0.0f;
        for (int l = 0; l < LL; ++l) { float e = __expf(rhos[l] - mx); rho_n[l] = e; s += e; }
        for (int l = 0; l < LL; ++l) rho_n[l] /= s;
    }
    if (tid < MM) {
        rowptr_s[tid] = rptr_rb[r * 513 + tid];
        rp_coef[tid] = row_offf[tid] * (1.0f - 2.0f * (float)synd[b * MM + tid]);
    }
    if (tid == MM) rowptr_s[MM] = rptr_rb[r * 513 + MM];
    if (tid < COLSB) {
        int j = r * COLSB + tid;
        float lj = llrs[j];
        llrs_s[tid] = lj;
        colsum_s[tid] = lj * w_llr[j];     // layer-0 colsum: msgs are zero
        ef_s[tid] = 1.0f - (float)errs[b * NN + j];
        bel_s[tid] = 0.0f;
        ncs_s[tid] = 0.0f;
    }

    int cnt = rptr_rb[r * 513 + MM];
    if (cnt > SLOTS) cnt = SLOTS;
    const int s0 = 4 * tid;                // this thread's first local slot

    // per-thread contiguous edge state (slice-major, row-sorted)
    unsigned idx[4];
    float msg[4], d_r[4];
    #pragma unroll
    for (int k = 0; k < 4; ++k) {
        int e = r * SLOTS + s0 + k;
        idx[k] = edge_cs[(s0 + k) < cnt ? e : r * SLOTS];   // clone first edge
        msg[k] = 0.0f;
    }
    __syncthreads();

    float loss = 0.0f;

    for (int l = 0; l < LL; ++l) {
        const float rw = resw[l];
        const int par = l & 1;
        float* pp_b = pp + ((size_t)par * BB + b) * RR * MM;

        // ---- B: prefetch weights (aligned float4) + per-edge tanh ----
        const float4 mq = *(const float4*)(mwde_p + ((size_t)(l * RR + r) * SLOTS) + s0);
        float4 wq = make_float4(0.f, 0.f, 0.f, 0.f);
        if (l + 1 < LL)
            wq = *(const float4*)(wde_p + ((size_t)((l + 1) * RR + r) * SLOTS) + s0);
        const float mv[4] = {mq.x, mq.y, mq.z, mq.w};
        const float wn[4] = {wq.x, wq.y, wq.z, wq.w};

        #pragma unroll
        for (int k = 0; k < 4; ++k) {
            int jl = idx[k] & 255u;                           // local col (slice-aligned)
            float en = colsum_s[jl] - msg[k];
            float t = __expf(en);                             // tanh(en/2)=1-2/(e^en+1)
            float d = 1.0f - 2.0f * __builtin_amdgcn_rcpf(t + 1.0f);
            if (d == 0.0f) d = 1.0f;                          // ref: where(d==0,1,d)
            d = fminf(fmaxf(d, -1.0f + EPSV), 1.0f - EPSV);
            d_r[k] = d;
        }
        *(float4*)&d_sb[s0] = make_float4(d_r[0], d_r[1], d_r[2], d_r[3]);
        __syncthreads();

        // ---- C: per-row PARTIAL products (in-slice deg ~5) -> coherent store ----
        if (tid < MM) {
            int lo = rowptr_s[tid], hi = rowptr_s[tid + 1];
            if (hi > SLOTS) hi = SLOTS;
            float p = 1.0f;
            for (int s = lo; s < hi; ++s) p *= d_sb[s];
            __hip_atomic_store(&pp_b[r * MM + tid], p,
                               __ATOMIC_RELAXED, __HIP_MEMORY_SCOPE_AGENT);
        }
        grid_barrier(&bar_b[l]);

        // ---- combine: full row product = rp_coef * prod of 8 partials ----
        if (tid < MM) {
            float p = rp_coef[tid];
            #pragma unroll
            for (int r2 = 0; r2 < RR; ++r2)
                p *= __hip_atomic_load(&pp_b[r2 * MM + tid],
                                       __ATOMIC_RELAXED, __HIP_MEMORY_SCOPE_AGENT);
            rowprod_s[tid] = p;
        }
        __syncthreads();

        // ---- D: atanh + msg update + LOCAL scatter (bel + next colsum) ----
        #pragma unroll
        for (int k = 0; k < 4; ++k) {
            int il = idx[k] >> 16;
            int jl = idx[k] & 255u;
            float rq = rowprod_s[il] * __builtin_amdgcn_rcpf(d_r[k]);
            // sgn*2*atanh(x) = 2*atanh(sgn*x); sgn folded into rp_coef
            float v = __logf(1.0f + rq) - __logf(1.0f - rq) + rw * msg[k];
            msg[k] = v;
            if (s0 + k < cnt) {
                atomicAdd(&bel_s[jl], v * mv[k]);
                if (l + 1 < LL) atomicAdd(&ncs_s[jl], v * wn[k]);
            }
        }
        __syncthreads();

        // ---- E: loss + next colsum on OWNED 256 columns (all local) ----
        if (tid < COLSB) {
            int j = r * COLSB + tid;
            float bel = llrs_s[tid] * mw_llr[l * NN + j] + bel_s[tid];
            bel_s[tid] = 0.0f;
            float sp = fmaxf(bel, 0.0f) + log1pf(__expf(-fabsf(bel)));  // softplus
            loss += rho_n[l] * (sp - ef_s[tid] * bel);
            if (l + 1 < LL) {
                colsum_s[tid] = llrs_s[tid] * w_llr[(l + 1) * NN + j] + ncs_s[tid];
                ncs_s[tid] = 0.0f;
            }
        }
        __syncthreads();
        // pp parity double-buffer: a straggler still combining layer l reads
        // pp[par] while others write pp[par^1] at C(l+1); layer l+2's reuse of
        // pp[par] is fenced by barrier(l+1), which the straggler must join
        // after its combine(l). Safe.
    }

    // ---- block reduction of loss, then one global atomic ----
    #pragma unroll
    for (int off = 32; off > 0; off >>= 1) loss += __shfl_down(loss, off);
    if (lane == 0) red[wave] = loss;
    __syncthreads();
    if (wave == 0) {
        float v = (lane < 16) ? red[lane] : 0.0f;
        #pragma unroll
        for (int off = 8; off > 0; off >>= 1) v += __shfl_down(v, off);
        if (lane == 0) atomicAdd(out, v * 0.25f);
    }
}

extern "C" void kernel_launch(void* const* d_in, const int* in_sizes, int n_in,
                              void* d_out, int out_size, void* d_ws, size_t ws_size,
                              hipStream_t stream) {
    const int*   synd  = (const int*)  d_in[0];
    const int*   errs  = (const int*)  d_in[1];
    const float* H     = (const float*)d_in[2];
    const float* llrs  = (const float*)d_in[3];
    const float* w_de  = (const float*)d_in[4];
    const float* w_llr = (const float*)d_in[5];
    const float* mw_de = (const float*)d_in[6];
    const float* mw_llr= (const float*)d_in[7];
    const float* rhos  = (const float*)d_in[8];
    const float* resw  = (const float*)d_in[9];

    char* ws = (char*)d_ws;
    int*      row_deg  = (int*)     (ws + WS_ROW_DEG);
    int*      row_pad  = (int*)     (ws + WS_ROW_PAD);
    float*    row_offf = (float*)   (ws + WS_ROW_OFFF);
    int*      deg_rb   = (int*)     (ws + WS_DEG_RB);
    int*      rptr_rb  = (int*)     (ws + WS_RPTR_RB);
    unsigned* edge_cs  = (unsigned*)(ws + WS_EDGE_CS);
    float*    wde_p    = (float*)   (ws + WS_WDE_P);
    float*    mwde_p   = (float*)   (ws + WS_MWDE_P);
    float*    pp       = (float*)   (ws + WS_PP);
    int*      bar      = (int*)     (ws + WS_BAR);
    float*    out      = (float*)d_out;

    hipMemsetAsync(bar, 0, BB * 64 * sizeof(int), stream);
    hipMemsetAsync(d_out, 0, sizeof(float), stream);

    build_rows<<<MM, 64, 0, stream>>>(H, row_deg, row_pad, row_offf);
    count_slices<<<1, 512, 0, stream>>>(row_deg, row_pad, deg_rb);
    scan_slices<<<RR, 512, 0, stream>>>(deg_rb, rptr_rb);
    fill_cs<<<1, 512, 0, stream>>>(row_deg, row_pad, rptr_rb, edge_cs);
    gather_weights<<<(LL * RR * SLOTS) / 256, 256, 0, stream>>>(w_de, mw_de, edge_cs,
                                                                rptr_rb, wde_p, mwde_p);
    nbp_main<<<BB * RR, NT, 0, stream>>>(synd, errs, llrs, w_llr, mw_llr, rhos, resw,
                                         rptr_rb, row_offf, edge_cs, wde_p, mwde_p,
                                         pp, bar, out);
}